// Round 6
// baseline (346.340 us; speedup 1.0000x reference)
//
#include <hip/hip_runtime.h>
#include <cstdint>

#define N_ANCH 8400
#define WMAX   132          // ceil(8400/64)
#define NB     (WMAX * 64)  // padded box slots: 8448
#define NT     512          // k_scan threads (8 waves)
#define NWAVE  8
#define NI     9            // gl16 issues per wave per batch (8*9=72 slots >= 1 diag + 64 cand)
#define WLIM   80           // pipelined path supports W <= 80 (this input: W=66)
#define STRIDEW 82          // u64 per pan slot (656 B; covers 2*40 words for W<=80)

__device__ __forceinline__ uint64_t readlane64(uint64_t v, int lane) {
  unsigned lo = (unsigned)__builtin_amdgcn_readlane((int)(unsigned)(v & 0xffffffffull), lane);
  unsigned hi = (unsigned)__builtin_amdgcn_readlane((int)(unsigned)(v >> 32), lane);
  return ((uint64_t)hi << 32) | lo;
}

__device__ __forceinline__ void gl16(const void* g, void* l) {
  __builtin_amdgcn_global_load_lds((const __attribute__((address_space(1))) uint32_t*)g,
                                   (__attribute__((address_space(3))) uint32_t*)l, 16, 0, 0);
}

// Kernel A: exact stable rank (descending score, invalid -> -inf, ties by index),
// scatter boxes/scores into sorted order, count valid. (verified)
__global__ __launch_bounds__(256) void k_rank(const float* __restrict__ in,
                                              float* __restrict__ scores_s,
                                              float4* __restrict__ boxes_s,
                                              unsigned* __restrict__ nvp) {
  __shared__ alignas(16) float sc[N_ANCH];
  __shared__ int part[256];
  const int tid = threadIdx.x;
  const float* srow = in + 4 * N_ANCH;
  for (int j = tid; j < N_ANCH; j += 256) sc[j] = srow[j];
  __syncthreads();
  const int il = tid & 63, q = tid >> 6;
  const int i = blockIdx.x * 64 + il;
  const float si = (i < N_ANCH) ? sc[i] : 0.0f;
  const bool valid = si > 0.5f;
  const float key = valid ? si : -INFINITY;
  int cnt = 0;
  const float4* sc4 = (const float4*)sc;
  const int jb = q * (N_ANCH / 4);
  for (int jj = 0; jj < (N_ANCH / 16); ++jj) {
    float4 v = sc4[q * (N_ANCH / 16) + jj];
    int j0 = jb + jj * 4;
    float k0 = (v.x > 0.5f) ? v.x : -INFINITY;
    float k1 = (v.y > 0.5f) ? v.y : -INFINITY;
    float k2 = (v.z > 0.5f) ? v.z : -INFINITY;
    float k3 = (v.w > 0.5f) ? v.w : -INFINITY;
    cnt += (k0 > key) || (k0 == key && (j0 + 0) < i);
    cnt += (k1 > key) || (k1 == key && (j0 + 1) < i);
    cnt += (k2 > key) || (k2 == key && (j0 + 2) < i);
    cnt += (k3 > key) || (k3 == key && (j0 + 3) < i);
  }
  part[tid] = cnt;
  __syncthreads();
  if (q == 0 && i < N_ANCH) {
    int r = part[il] + part[64 + il] + part[128 + il] + part[192 + il];
    float cx = in[0 * N_ANCH + i], cy = in[1 * N_ANCH + i];
    float w  = in[2 * N_ANCH + i], h  = in[3 * N_ANCH + i];
    float x1 = cx - w * 0.5f, y1 = cy - h * 0.5f;
    float x2 = cx + w * 0.5f, y2 = cy + h * 0.5f;
    boxes_s[r] = make_float4(x1, y1, x2, y2);
    scores_s[r] = valid ? si : 0.0f;
    if (valid) atomicAdd(nvp, 1u);
  }
}

// Kernel B: full sup matrix, row-major with EVEN stride Wp (16B-aligned rows),
// plus contiguous diag[]. Exact verified IoU float path.
__global__ __launch_bounds__(256) void k_sup(const float4* __restrict__ boxes_s,
                                             const unsigned* __restrict__ nvp,
                                             unsigned long long* __restrict__ sup,
                                             unsigned long long* __restrict__ diag) {
  const int nv = (int)*nvp;
  const int W = (nv + 63) >> 6;
  const int Wp = (W + 1) & ~1;
  const int w = blockIdx.x;
  if (w >= W) return;
  __shared__ float bx1[64], by1[64], bx2[64], by2[64], bar[64];
  const int tid = threadIdx.x;
  if (tid < 64) {
    int j = w * 64 + tid;
    float4 b = (j < N_ANCH) ? boxes_s[j] : make_float4(0.f, 0.f, 0.f, 0.f);
    bx1[tid] = b.x; by1[tid] = b.y; bx2[tid] = b.z; by2[tid] = b.w;
    bar[tid] = (b.z - b.x) * (b.w - b.y);
  }
  __syncthreads();
  const int i = blockIdx.y * 256 + tid;
  if (i >= nv) return;
  float4 bi = boxes_s[i];
  float ai = (bi.z - bi.x) * (bi.w - bi.y);
  const int jmax = nv - w * 64;
  uint64_t bits = 0;
  #pragma unroll 8
  for (int l = 0; l < 64; ++l) {
    float lx = fmaxf(bi.x, bx1[l]);
    float ly = fmaxf(bi.y, by1[l]);
    float rx = fminf(bi.z, bx2[l]);
    float ry = fminf(bi.w, by2[l]);
    float dx = fmaxf(rx - lx, 0.0f);
    float dy = fmaxf(ry - ly, 0.0f);
    float inter = dx * dy;
    asm volatile("" : "+v"(inter));           // block fma-contraction into union
    float uni = (ai + bar[l]) - inter;        // reference op order
    float iou = inter / uni;                  // IEEE f32 div, matches numpy
    bits |= ((uint64_t)((l < jmax) && (iou > 0.5f))) << l;
  }
  sup[(size_t)i * Wp + w] = bits;
  if (w == (i >> 6)) diag[i] = bits;
}

// Kernel C: single-workgroup scan with DEPTH-2 SPECULATIVE PREFETCH:
// candidates of block k+2 (superset of final kept rows) are extracted at iter k
// and their sup row-slices DMA'd to LDS (global_load_lds, counted vmcnt(9)).
// Apply phase is LDS-only; memory latency hidden across 2 iterations.
__global__ __launch_bounds__(NT) void k_scan(const float* __restrict__ scores_s,
                                             const float4* __restrict__ boxes_s,
                                             const unsigned long long* __restrict__ sup_,
                                             const unsigned long long* __restrict__ diag_g,
                                             const unsigned* __restrict__ nvp,
                                             float* __restrict__ out) {
  __shared__ uint64_t keep_s[WMAX];
  __shared__ uint64_t pan[3][64 * STRIDEW];   // 125952 B
  __shared__ uint64_t diag_lds[3][64];        // 1536 B
  __shared__ uint64_t dump[128];              // 1024 B garbage target for dummy DMA
  __shared__ unsigned rowbit[3][64];          // candidate slot -> row bit
  __shared__ unsigned slotmap[3][64];         // row bit -> candidate slot
  __shared__ unsigned ncand[3];
  const uint64_t* sup = (const uint64_t*)sup_;
  const uint64_t* diag64 = (const uint64_t*)diag_g;
  const int tid = threadIdx.x;
  const int lane = tid & 63;
  const int q = tid >> 6;
  const int nv = (int)*nvp;
  const int W  = (nv + 63) >> 6;
  const int Wp = (W + 1) & ~1;

  for (int idx = tid; idx < WMAX; idx += NT) {
    uint64_t v = 0; int base = idx * 64;
    if (base < nv) { int rem = nv - base; v = (rem >= 64) ? ~0ull : ((1ull << rem) - 1ull); }
    keep_s[idx] = v;
  }
  __syncthreads();

  if (W > 0 && W <= WLIM) {
    // ---------------- pipelined path ----------------
    auto extract = [&](int K) {          // run by ONE wave
      const int stg = K % 3;
      if (K >= W) { if (lane == 0) ncand[stg] = 0; return; }
      uint64_t word = keep_s[K];
      int set = (int)((word >> lane) & 1ull);
      unsigned slot = (unsigned)__popcll(word & ((1ull << lane) - 1ull));
      if (set) rowbit[stg][slot] = (unsigned)lane;
      slotmap[stg][lane] = set ? slot : 0xFFFFFFFFu;
      if (lane == 0) ncand[stg] = (unsigned)__popcll(word);
    };
    auto issue_batch = [&](int K) {      // run by ALL waves; exactly NI gl16 per wave
      const int stg = K % 3;
      const int se = (K + 1) & ~1;
      const int nhalf = (W > se) ? ((W - se + 1) >> 1) : 0;
      const int nc = (K < W) ? (int)ncand[stg] : 0;
      #pragma unroll 1
      for (int j = 0; j < NI; ++j) {
        int s = q * NI + j;              // 0..71
        const uint64_t* gp; uint64_t* lp; int lim;
        if (s == 0 && K < W) {
          gp = diag64 + (size_t)K * 64 + 2 * lane;
          lp = &diag_lds[stg][0];
          lim = 32;
        } else if (s >= 1 && s <= 64 && (s - 1) < nc && nhalf > 0) {
          int rb = (int)rowbit[stg][s - 1];
          size_t row = (size_t)K * 64 + rb;
          gp = sup + row * Wp + se + 2 * lane;
          lp = &pan[stg][(size_t)(s - 1) * STRIDEW];
          lim = nhalf;
        } else {
          gp = sup + 2 * lane;           // harmless dummy read
          lp = &dump[0];
          lim = 64;
        }
        if (lane < lim) gl16(gp, lp);    // lane 0 always active -> always issues
      }
    };

    if (q == 0) extract(0);
    else if (q == 1) extract(1);
    asm volatile("s_waitcnt lgkmcnt(0)" ::: "memory");
    __builtin_amdgcn_sched_barrier(0);
    __builtin_amdgcn_s_barrier();
    __builtin_amdgcn_sched_barrier(0);
    issue_batch(0);
    issue_batch(1);

    for (int k = 0; k < W; ++k) {
      // batch k drained; batch k+1 stays in flight (counted, never 0 mid-loop)
      asm volatile("s_waitcnt vmcnt(9) lgkmcnt(0)" ::: "memory");
      __builtin_amdgcn_sched_barrier(0);
      __builtin_amdgcn_s_barrier();
      __builtin_amdgcn_sched_barrier(0);

      if (q == 0) {
        // serial diag resolve of block k (LDS-resident word)
        uint64_t cur = diag_lds[k % 3][lane];
        uint64_t bk = keep_s[k];
        uint64_t cand = bk;
        while (cand) {
          int r = (int)__builtin_ctzll(cand);
          uint64_t sr = readlane64(cur, r);
          uint64_t m = sr & ~((2ull << r) - 1ull);
          cand &= ~(1ull << r);
          cand &= ~m;
          bk   &= ~m;
        }
        if (lane == 0) keep_s[k] = bk;
      } else if (q == 1) {
        extract(k + 2);                  // speculative superset, 2 ahead
      }
      asm volatile("s_waitcnt lgkmcnt(0)" ::: "memory");
      __builtin_amdgcn_sched_barrier(0);
      __builtin_amdgcn_s_barrier();
      __builtin_amdgcn_sched_barrier(0);

      issue_batch(k + 2);                // loads land by iter k+2

      // apply: LDS-only OR of kept rows' slice words
      {
        uint64_t bk2 = keep_s[k];
        int wd = k + 1 + tid;
        if (bk2 && wd < W) {
          const int stg = k % 3;
          const int se = (k + 1) & ~1;
          uint64_t acc = 0;
          uint64_t rem = bk2;
          while (rem) {
            int r = (int)__builtin_ctzll(rem);
            rem &= rem - 1;
            unsigned slot = slotmap[stg][r];   // kept ⊆ candidates, always valid
            acc |= pan[stg][(size_t)slot * STRIDEW + (wd - se)];
          }
          keep_s[wd] &= ~acc;
        }
      }
      asm volatile("s_waitcnt lgkmcnt(0)" ::: "memory");
      __builtin_amdgcn_sched_barrier(0);
      __builtin_amdgcn_s_barrier();
      __builtin_amdgcn_sched_barrier(0);
    }
    asm volatile("s_waitcnt vmcnt(0)" ::: "memory");
  } else if (W > 0) {
    // ---------------- fallback direct-load path (W > WLIM; not hit here) ----------------
    uint64_t dw = 0;
    if (q == 0) dw = (uint64_t)diag_g[lane];
    __syncthreads();
    for (int k = 0; k < W; ++k) {
      if (q == 0) {
        uint64_t cur = dw;
        if (k + 1 < W) dw = (uint64_t)diag_g[(size_t)(k + 1) * 64 + lane];
        uint64_t bk = keep_s[k];
        uint64_t cand = bk;
        while (cand) {
          int r = (int)__builtin_ctzll(cand);
          uint64_t sr = readlane64(cur, r);
          uint64_t m = sr & ~((2ull << r) - 1ull);
          cand &= ~(1ull << r); cand &= ~m; bk &= ~m;
        }
        if (lane == 0) keep_s[k] = bk;
      }
      __syncthreads();
      const uint64_t bk2 = keep_s[k];
      if (bk2) {
        const int rowbase = k * 64;
        for (int wd = k + 1 + tid; wd < W; wd += NT) {
          uint64_t acc = 0, rem = bk2;
          while (rem) {
            int r = (int)__builtin_ctzll(rem); rem &= rem - 1;
            acc |= sup[(size_t)(rowbase + r) * Wp + wd];
          }
          keep_s[wd] &= ~acc;
        }
      }
      __syncthreads();
    }
  }
  __syncthreads();

  // --- emit output ---
  for (int r = tid; r < N_ANCH; r += NT) {
    bool kept = (r < nv) && ((keep_s[r >> 6] >> (r & 63)) & 1ull);
    float4 b = kept ? boxes_s[r] : make_float4(0.f, 0.f, 0.f, 0.f);
    float s = kept ? scores_s[r] : 0.0f;
    out[r * 5 + 0] = b.x;
    out[r * 5 + 1] = b.y;
    out[r * 5 + 2] = b.z;
    out[r * 5 + 3] = b.w;
    out[r * 5 + 4] = s;
  }
}

extern "C" void kernel_launch(void* const* d_in, const int* in_sizes, int n_in,
                              void* d_out, int out_size, void* d_ws, size_t ws_size,
                              hipStream_t stream) {
  const float* in = (const float*)d_in[0];
  float* out = (float*)d_out;
  uint8_t* ws = (uint8_t*)d_ws;
  unsigned* nvp = (unsigned*)ws;                                       // 64 B
  float* scores_s = (float*)(ws + 64);                                 // 33600 B
  float4* boxes_s = (float4*)(ws + 64 + 33600);                        // NB*16 = 135168 B
  unsigned long long* diag = (unsigned long long*)(ws + 64 + 33600 + (size_t)NB * 16);   // NB*8
  unsigned long long* sup  = (unsigned long long*)(ws + 64 + 33600 + (size_t)NB * 24);   // ~2.3 MB

  (void)hipMemsetAsync(ws, 0, 64, stream);
  k_rank<<<dim3(WMAX), dim3(256), 0, stream>>>(in, scores_s, boxes_s, nvp);
  k_sup<<<dim3(WMAX, (N_ANCH + 255) / 256), dim3(256), 0, stream>>>(boxes_s, nvp, sup, diag);
  k_scan<<<dim3(1), dim3(NT), 0, stream>>>(scores_s, boxes_s, sup, diag, nvp, out);
}

// Round 7
// 286.591 us; speedup vs baseline: 1.2085x; 1.2085x over previous
//
#include <hip/hip_runtime.h>
#include <cstdint>

#define N_ANCH 8400
#define WMAX   132          // ceil(8400/64)
#define NB     (WMAX * 64)  // padded box slots: 8448
#define NT     512          // k_scan threads (8 waves)
#define NI     9            // gl16 issues per wave per batch (8*9=72 slots >= 1 diag + 64 cand)
#define WLIM   80           // pipelined path supports W <= 80 (this input: W=66)
#define STRIDEW 82          // u64 per pan slot (656 B; covers 2*40 words for W<=80)

__device__ __forceinline__ uint64_t readlane64(uint64_t v, int lane) {
  unsigned lo = (unsigned)__builtin_amdgcn_readlane((int)(unsigned)(v & 0xffffffffull), lane);
  unsigned hi = (unsigned)__builtin_amdgcn_readlane((int)(unsigned)(v >> 32), lane);
  return ((uint64_t)hi << 32) | lo;
}

__device__ __forceinline__ void gl16(const void* g, void* l) {
  __builtin_amdgcn_global_load_lds((const __attribute__((address_space(1))) uint32_t*)g,
                                   (__attribute__((address_space(3))) uint32_t*)l, 16, 0, 0);
}

// Kernel A: exact stable rank (descending score, invalid -> -inf, ties by index),
// scatter boxes/scores into sorted order, count valid. (verified)
__global__ __launch_bounds__(256) void k_rank(const float* __restrict__ in,
                                              float* __restrict__ scores_s,
                                              float4* __restrict__ boxes_s,
                                              unsigned* __restrict__ nvp) {
  __shared__ alignas(16) float sc[N_ANCH];
  __shared__ int part[256];
  const int tid = threadIdx.x;
  const float* srow = in + 4 * N_ANCH;
  for (int j = tid; j < N_ANCH; j += 256) sc[j] = srow[j];
  __syncthreads();
  const int il = tid & 63, q = tid >> 6;
  const int i = blockIdx.x * 64 + il;
  const float si = (i < N_ANCH) ? sc[i] : 0.0f;
  const bool valid = si > 0.5f;
  const float key = valid ? si : -INFINITY;
  int cnt = 0;
  const float4* sc4 = (const float4*)sc;
  const int jb = q * (N_ANCH / 4);
  for (int jj = 0; jj < (N_ANCH / 16); ++jj) {
    float4 v = sc4[q * (N_ANCH / 16) + jj];
    int j0 = jb + jj * 4;
    float k0 = (v.x > 0.5f) ? v.x : -INFINITY;
    float k1 = (v.y > 0.5f) ? v.y : -INFINITY;
    float k2 = (v.z > 0.5f) ? v.z : -INFINITY;
    float k3 = (v.w > 0.5f) ? v.w : -INFINITY;
    cnt += (k0 > key) || (k0 == key && (j0 + 0) < i);
    cnt += (k1 > key) || (k1 == key && (j0 + 1) < i);
    cnt += (k2 > key) || (k2 == key && (j0 + 2) < i);
    cnt += (k3 > key) || (k3 == key && (j0 + 3) < i);
  }
  part[tid] = cnt;
  __syncthreads();
  if (q == 0 && i < N_ANCH) {
    int r = part[il] + part[64 + il] + part[128 + il] + part[192 + il];
    float cx = in[0 * N_ANCH + i], cy = in[1 * N_ANCH + i];
    float w  = in[2 * N_ANCH + i], h  = in[3 * N_ANCH + i];
    float x1 = cx - w * 0.5f, y1 = cy - h * 0.5f;
    float x2 = cx + w * 0.5f, y2 = cy + h * 0.5f;
    boxes_s[r] = make_float4(x1, y1, x2, y2);
    scores_s[r] = valid ? si : 0.0f;
    if (valid) atomicAdd(nvp, 1u);
  }
}

// Kernel B: full sup matrix, row-major with EVEN stride Wp (16B-aligned rows),
// plus contiguous diag[]. Exact verified IoU float path.
__global__ __launch_bounds__(256) void k_sup(const float4* __restrict__ boxes_s,
                                             const unsigned* __restrict__ nvp,
                                             unsigned long long* __restrict__ sup,
                                             unsigned long long* __restrict__ diag) {
  const int nv = (int)*nvp;
  const int W = (nv + 63) >> 6;
  const int Wp = (W + 1) & ~1;
  const int w = blockIdx.x;
  if (w >= W) return;
  __shared__ float bx1[64], by1[64], bx2[64], by2[64], bar[64];
  const int tid = threadIdx.x;
  if (tid < 64) {
    int j = w * 64 + tid;
    float4 b = (j < N_ANCH) ? boxes_s[j] : make_float4(0.f, 0.f, 0.f, 0.f);
    bx1[tid] = b.x; by1[tid] = b.y; bx2[tid] = b.z; by2[tid] = b.w;
    bar[tid] = (b.z - b.x) * (b.w - b.y);
  }
  __syncthreads();
  const int i = blockIdx.y * 256 + tid;
  if (i >= nv) return;
  float4 bi = boxes_s[i];
  float ai = (bi.z - bi.x) * (bi.w - bi.y);
  const int jmax = nv - w * 64;
  uint64_t bits = 0;
  #pragma unroll 8
  for (int l = 0; l < 64; ++l) {
    float lx = fmaxf(bi.x, bx1[l]);
    float ly = fmaxf(bi.y, by1[l]);
    float rx = fminf(bi.z, bx2[l]);
    float ry = fminf(bi.w, by2[l]);
    float dx = fmaxf(rx - lx, 0.0f);
    float dy = fmaxf(ry - ly, 0.0f);
    float inter = dx * dy;
    asm volatile("" : "+v"(inter));           // block fma-contraction into union
    float uni = (ai + bar[l]) - inter;        // reference op order
    float iou = inter / uni;                  // IEEE f32 div, matches numpy
    bits |= ((uint64_t)((l < jmax) && (iou > 0.5f))) << l;
  }
  sup[(size_t)i * Wp + w] = bits;
  if (w == (i >> 6)) diag[i] = bits;
}

// Kernel C: single-workgroup scan with depth-2 speculative prefetch.
// Candidates of block k+2 extracted at iter k, row-slices DMA'd to LDS.
// Dummy DMAs run with 1-lane exec (count padding only, ~no traffic).
// 2 barriers/iter; counted vmcnt(9) folded into end-of-iter barrier.
__global__ __launch_bounds__(NT) void k_scan(const float* __restrict__ scores_s,
                                             const float4* __restrict__ boxes_s,
                                             const unsigned long long* __restrict__ sup_,
                                             const unsigned long long* __restrict__ diag_g,
                                             const unsigned* __restrict__ nvp,
                                             float* __restrict__ out) {
  __shared__ uint64_t keep_s[WMAX];
  __shared__ uint64_t pan[3][64 * STRIDEW];   // 125952 B
  __shared__ uint64_t diag_lds[3][64];        // 1536 B
  __shared__ uint64_t dump[16];               // dummy DMA target (lane0 only)
  __shared__ unsigned rowbit[3][64];          // candidate slot -> row bit
  __shared__ unsigned ncand[3];
  const uint64_t* sup = (const uint64_t*)sup_;
  const uint64_t* diag64 = (const uint64_t*)diag_g;
  const int tid = threadIdx.x;
  const int lane = tid & 63;
  const int q = tid >> 6;
  const int nv = (int)*nvp;
  const int W  = (nv + 63) >> 6;
  const int Wp = (W + 1) & ~1;

  for (int idx = tid; idx < WMAX; idx += NT) {
    uint64_t v = 0; int base = idx * 64;
    if (base < nv) { int rem = nv - base; v = (rem >= 64) ? ~0ull : ((1ull << rem) - 1ull); }
    keep_s[idx] = v;
  }
  __syncthreads();

  if (W > 0 && W <= WLIM) {
    // ---------------- pipelined path ----------------
    auto extract = [&](int K) {          // run by ONE wave
      const int stg = K % 3;
      if (K >= W) { if (lane == 0) ncand[stg] = 0; return; }
      uint64_t word = keep_s[K];
      int set = (int)((word >> lane) & 1ull);
      unsigned slot = (unsigned)__popcll(word & ((1ull << lane) - 1ull));
      if (set) rowbit[stg][slot] = (unsigned)lane;
      if (lane == 0) ncand[stg] = (unsigned)__popcll(word);
    };
    auto issue_batch = [&](int K) {      // ALL waves; exactly NI gl16 per wave
      const int stg = K % 3;
      const int se = (K + 1) & ~1;
      const int nhalf = (W > se) ? ((W - se + 1) >> 1) : 0;
      const int nc = (K < W) ? (int)ncand[stg] : 0;
      unsigned rbvec = rowbit[stg][lane];          // one vector ds_read per wave
      #pragma unroll
      for (int j = 0; j < NI; ++j) {
        int s = q * NI + j;              // 0..71, wave-uniform
        if (s == 0 && K < W) {
          if (lane < 32) gl16(diag64 + (size_t)K * 64 + 2 * lane, &diag_lds[stg][0]);
        } else if (s >= 1 && s <= 64 && (s - 1) < nc && nhalf > 0) {
          int rb = __builtin_amdgcn_readlane((int)rbvec, s - 1);   // SALU, no LDS chain
          size_t row = (size_t)K * 64 + (unsigned)rb;
          if (lane < nhalf) gl16(sup + row * Wp + se + 2 * lane,
                                 &pan[stg][(size_t)(s - 1) * STRIDEW]);
        } else {
          if (lane < 1) gl16(sup, &dump[0]);   // slim dummy: 16 B, count-only
        }
      }
    };

    // prologue: batches 0 and 1 in flight; batch 0 drained before loop
    if (q == 0) extract(0);
    else if (q == 1) extract(1);
    asm volatile("s_waitcnt lgkmcnt(0)" ::: "memory");
    __builtin_amdgcn_sched_barrier(0);
    __builtin_amdgcn_s_barrier();
    __builtin_amdgcn_sched_barrier(0);
    issue_batch(0);
    issue_batch(1);
    asm volatile("s_waitcnt vmcnt(9) lgkmcnt(0)" ::: "memory");
    __builtin_amdgcn_sched_barrier(0);
    __builtin_amdgcn_s_barrier();
    __builtin_amdgcn_sched_barrier(0);

    for (int k = 0; k < W; ++k) {
      const int stg = k % 3;
      // --- phase B: wave0 serial diag resolve; wave1 extract k+2 ---
      if (q == 0) {
        uint64_t cur = diag_lds[stg][lane];
        uint64_t bk = keep_s[k];
        uint64_t cand = bk;
        while (cand) {
          int r = (int)__builtin_ctzll(cand);
          uint64_t sr = readlane64(cur, r);
          uint64_t m = sr & ~((2ull << r) - 1ull);
          cand &= ~(1ull << r);
          cand &= ~m;
          bk   &= ~m;
        }
        if (lane == 0) keep_s[k] = bk;
      } else if (q == 1) {
        extract(k + 2);                  // speculative superset, 2 ahead
      }
      asm volatile("s_waitcnt lgkmcnt(0)" ::: "memory");
      __builtin_amdgcn_sched_barrier(0);
      __builtin_amdgcn_s_barrier();
      __builtin_amdgcn_sched_barrier(0);

      // --- phase C: issue batch k+2; apply block k from LDS (slot-indexed) ---
      issue_batch(k + 2);
      {
        uint64_t bk2 = keep_s[k];
        int wd = k + 1 + tid;
        if (bk2 && wd < W) {
          const int se = (k + 1) & ~1;
          const int nc2 = (int)ncand[stg];
          uint64_t acc = 0;
          for (int s = 0; s < nc2; ++s) {          // independent LDS reads
            unsigned rb = rowbit[stg][s];
            uint64_t mask = (uint64_t)0 - ((bk2 >> rb) & 1ull);
            acc |= pan[stg][(size_t)s * STRIDEW + (wd - se)] & mask;
          }
          keep_s[wd] &= ~acc;
        }
      }
      asm volatile("s_waitcnt vmcnt(9) lgkmcnt(0)" ::: "memory");
      __builtin_amdgcn_sched_barrier(0);
      __builtin_amdgcn_s_barrier();
      __builtin_amdgcn_sched_barrier(0);
    }
    asm volatile("s_waitcnt vmcnt(0)" ::: "memory");
  } else if (W > 0) {
    // ---------------- fallback direct-load path (W > WLIM; not hit here) ----------------
    uint64_t dw = 0;
    if (q == 0) dw = (uint64_t)diag_g[lane];
    __syncthreads();
    for (int k = 0; k < W; ++k) {
      if (q == 0) {
        uint64_t cur = dw;
        if (k + 1 < W) dw = (uint64_t)diag_g[(size_t)(k + 1) * 64 + lane];
        uint64_t bk = keep_s[k];
        uint64_t cand = bk;
        while (cand) {
          int r = (int)__builtin_ctzll(cand);
          uint64_t sr = readlane64(cur, r);
          uint64_t m = sr & ~((2ull << r) - 1ull);
          cand &= ~(1ull << r); cand &= ~m; bk &= ~m;
        }
        if (lane == 0) keep_s[k] = bk;
      }
      __syncthreads();
      const uint64_t bk2 = keep_s[k];
      if (bk2) {
        const int rowbase = k * 64;
        for (int wd = k + 1 + tid; wd < W; wd += NT) {
          uint64_t acc = 0, rem = bk2;
          while (rem) {
            int r = (int)__builtin_ctzll(rem); rem &= rem - 1;
            acc |= sup[(size_t)(rowbase + r) * Wp + wd];
          }
          keep_s[wd] &= ~acc;
        }
      }
      __syncthreads();
    }
  }
  __syncthreads();

  // --- emit output ---
  for (int r = tid; r < N_ANCH; r += NT) {
    bool kept = (r < nv) && ((keep_s[r >> 6] >> (r & 63)) & 1ull);
    float4 b = kept ? boxes_s[r] : make_float4(0.f, 0.f, 0.f, 0.f);
    float s = kept ? scores_s[r] : 0.0f;
    out[r * 5 + 0] = b.x;
    out[r * 5 + 1] = b.y;
    out[r * 5 + 2] = b.z;
    out[r * 5 + 3] = b.w;
    out[r * 5 + 4] = s;
  }
}

extern "C" void kernel_launch(void* const* d_in, const int* in_sizes, int n_in,
                              void* d_out, int out_size, void* d_ws, size_t ws_size,
                              hipStream_t stream) {
  const float* in = (const float*)d_in[0];
  float* out = (float*)d_out;
  uint8_t* ws = (uint8_t*)d_ws;
  unsigned* nvp = (unsigned*)ws;                                       // 64 B
  float* scores_s = (float*)(ws + 64);                                 // 33600 B
  float4* boxes_s = (float4*)(ws + 64 + 33600);                        // NB*16 = 135168 B
  unsigned long long* diag = (unsigned long long*)(ws + 64 + 33600 + (size_t)NB * 16);   // NB*8
  unsigned long long* sup  = (unsigned long long*)(ws + 64 + 33600 + (size_t)NB * 24);   // ~2.3 MB

  (void)hipMemsetAsync(ws, 0, 64, stream);
  k_rank<<<dim3(WMAX), dim3(256), 0, stream>>>(in, scores_s, boxes_s, nvp);
  k_sup<<<dim3(WMAX, (N_ANCH + 255) / 256), dim3(256), 0, stream>>>(boxes_s, nvp, sup, diag);
  k_scan<<<dim3(1), dim3(NT), 0, stream>>>(scores_s, boxes_s, sup, diag, nvp, out);
}

// Round 8
// 284.922 us; speedup vs baseline: 1.2156x; 1.0059x over previous
//
#include <hip/hip_runtime.h>
#include <cstdint>

#define N_ANCH 8400
#define WMAX   132          // ceil(8400/64)
#define NB     (WMAX * 64)  // padded box slots: 8448
#define NT     512          // k_scan threads: wave0 scans, all 8 waves emit
#define CSLOT  32           // register prefetch slots (candidate rows per block)

__device__ __forceinline__ uint64_t readlane64(uint64_t v, int lane) {
  unsigned lo = (unsigned)__builtin_amdgcn_readlane((int)(unsigned)(v & 0xffffffffull), lane);
  unsigned hi = (unsigned)__builtin_amdgcn_readlane((int)(unsigned)(v >> 32), lane);
  return ((uint64_t)hi << 32) | lo;
}
__device__ __forceinline__ uint64_t firstlane64(uint64_t v) {
  unsigned lo = (unsigned)__builtin_amdgcn_readfirstlane((int)(unsigned)(v & 0xffffffffull));
  unsigned hi = (unsigned)__builtin_amdgcn_readfirstlane((int)(unsigned)(v >> 32));
  return ((uint64_t)hi << 32) | lo;
}
__device__ __forceinline__ uint64_t shflxor64(uint64_t v, int m) {
  int lo = __shfl_xor((int)(unsigned)(v & 0xffffffffull), m, 64);
  int hi = __shfl_xor((int)(unsigned)(v >> 32), m, 64);
  return ((uint64_t)(unsigned)hi << 32) | (unsigned)lo;
}

// Kernel A: exact stable rank (descending score, invalid -> -inf, ties by index),
// scatter boxes/scores into sorted order, count valid. (verified)
__global__ __launch_bounds__(256) void k_rank(const float* __restrict__ in,
                                              float* __restrict__ scores_s,
                                              float4* __restrict__ boxes_s,
                                              unsigned* __restrict__ nvp) {
  __shared__ alignas(16) float sc[N_ANCH];
  __shared__ int part[256];
  const int tid = threadIdx.x;
  const float* srow = in + 4 * N_ANCH;
  for (int j = tid; j < N_ANCH; j += 256) sc[j] = srow[j];
  __syncthreads();
  const int il = tid & 63, q = tid >> 6;
  const int i = blockIdx.x * 64 + il;
  const float si = (i < N_ANCH) ? sc[i] : 0.0f;
  const bool valid = si > 0.5f;
  const float key = valid ? si : -INFINITY;
  int cnt = 0;
  const float4* sc4 = (const float4*)sc;
  const int jb = q * (N_ANCH / 4);
  for (int jj = 0; jj < (N_ANCH / 16); ++jj) {
    float4 v = sc4[q * (N_ANCH / 16) + jj];
    int j0 = jb + jj * 4;
    float k0 = (v.x > 0.5f) ? v.x : -INFINITY;
    float k1 = (v.y > 0.5f) ? v.y : -INFINITY;
    float k2 = (v.z > 0.5f) ? v.z : -INFINITY;
    float k3 = (v.w > 0.5f) ? v.w : -INFINITY;
    cnt += (k0 > key) || (k0 == key && (j0 + 0) < i);
    cnt += (k1 > key) || (k1 == key && (j0 + 1) < i);
    cnt += (k2 > key) || (k2 == key && (j0 + 2) < i);
    cnt += (k3 > key) || (k3 == key && (j0 + 3) < i);
  }
  part[tid] = cnt;
  __syncthreads();
  if (q == 0 && i < N_ANCH) {
    int r = part[il] + part[64 + il] + part[128 + il] + part[192 + il];
    float cx = in[0 * N_ANCH + i], cy = in[1 * N_ANCH + i];
    float w  = in[2 * N_ANCH + i], h  = in[3 * N_ANCH + i];
    float x1 = cx - w * 0.5f, y1 = cy - h * 0.5f;
    float x2 = cx + w * 0.5f, y2 = cy + h * 0.5f;
    boxes_s[r] = make_float4(x1, y1, x2, y2);
    scores_s[r] = valid ? si : 0.0f;
    if (valid) atomicAdd(nvp, 1u);
  }
}

// Kernel B: sup matrix, row-major stride Wp, UPPER TRIANGLE ONLY (w >= rowblock;
// the scan never reads w <= k), plus contiguous diag[]. Exact verified IoU path.
__global__ __launch_bounds__(256) void k_sup(const float4* __restrict__ boxes_s,
                                             const unsigned* __restrict__ nvp,
                                             unsigned long long* __restrict__ sup,
                                             unsigned long long* __restrict__ diag) {
  const int nv = (int)*nvp;
  const int W = (nv + 63) >> 6;
  const int Wp = (W + 1) & ~1;
  const int w = blockIdx.x;
  if (w >= W) return;
  if (w + 1 < (int)(blockIdx.y * 256) >> 6) return;   // whole block in lower triangle
  __shared__ float bx1[64], by1[64], bx2[64], by2[64], bar[64];
  const int tid = threadIdx.x;
  if (tid < 64) {
    int j = w * 64 + tid;
    float4 b = (j < N_ANCH) ? boxes_s[j] : make_float4(0.f, 0.f, 0.f, 0.f);
    bx1[tid] = b.x; by1[tid] = b.y; bx2[tid] = b.z; by2[tid] = b.w;
    bar[tid] = (b.z - b.x) * (b.w - b.y);
  }
  __syncthreads();
  const int i = blockIdx.y * 256 + tid;
  if (i >= nv) return;
  if (w < (i >> 6)) return;                            // lower triangle: never read
  float4 bi = boxes_s[i];
  float ai = (bi.z - bi.x) * (bi.w - bi.y);
  const int jmax = nv - w * 64;
  uint64_t bits = 0;
  #pragma unroll 8
  for (int l = 0; l < 64; ++l) {
    float lx = fmaxf(bi.x, bx1[l]);
    float ly = fmaxf(bi.y, by1[l]);
    float rx = fminf(bi.z, bx2[l]);
    float ry = fminf(bi.w, by2[l]);
    float dx = fmaxf(rx - lx, 0.0f);
    float dy = fmaxf(ry - ly, 0.0f);
    float inter = dx * dy;
    asm volatile("" : "+v"(inter));           // block fma-contraction into union
    float uni = (ai + bar[l]) - inter;        // reference op order
    float iou = inter / uni;                  // IEEE f32 div, matches numpy
    bits |= ((uint64_t)((l < jmax) && (iou > 0.5f))) << l;
  }
  sup[(size_t)i * Wp + w] = bits;
  if (w == (i >> 6)) diag[i] = bits;
}

// Kernel C: SINGLE-WAVE scan, zero barriers. Register-resident candidate
// prefetch (pre[CSLOT], issued 1 iteration ahead from the monotone superset
// keep word); kept-masked overflow via batched-8 direct loads; tail words
// (>= k+65) via per-lane-row load + shfl-OR reduce. Waves 1-7 only emit.
__global__ __launch_bounds__(NT) void k_scan(const float* __restrict__ scores_s,
                                             const float4* __restrict__ boxes_s,
                                             const unsigned long long* __restrict__ sup_,
                                             const unsigned long long* __restrict__ diag_g,
                                             const unsigned* __restrict__ nvp,
                                             float* __restrict__ out) {
  __shared__ uint64_t keep_s[WMAX];
  const uint64_t* sup = (const uint64_t*)sup_;
  const uint64_t* diag64 = (const uint64_t*)diag_g;
  const int tid = threadIdx.x;
  const int lane = tid & 63;
  const int wave = tid >> 6;
  const int nv = (int)*nvp;
  const int W  = (nv + 63) >> 6;
  const int Wp = (W + 1) & ~1;

  for (int idx = tid; idx < WMAX; idx += NT) {
    uint64_t v = 0; int base = idx * 64;
    if (base < nv) { int rem = nv - base; v = (rem >= 64) ? ~0ull : ((1ull << rem) - 1ull); }
    keep_s[idx] = v;
  }
  __syncthreads();

  if (wave == 0 && W > 0) {
    uint64_t pre[CSLOT];
    uint64_t bkw = firstlane64(keep_s[0]);   // candidate word of block 0
    uint64_t ovw = 0;                        // candidates beyond CSLOT
    uint64_t dw  = diag64[lane];             // diag word, row `lane` of block 0

    // prologue: issue register prefetch for block 0
    {
      uint64_t remc = bkw;
      const int wd = 1 + lane;
      #pragma unroll
      for (int s = 0; s < CSLOT; ++s) {
        int r = remc ? (int)__builtin_ctzll(remc) : 0;
        bool valid = (remc != 0);
        remc &= remc - 1;
        pre[s] = (valid && wd < W) ? sup[(size_t)r * Wp + wd] : 0ull;
      }
      ovw = remc;
    }

    for (int k = 0; k < W; ++k) {
      // ---- resolve block k (serial ctz-skip chain; wave-uniform scalars) ----
      uint64_t bk = bkw;
      {
        uint64_t cand = bk;
        while (cand) {
          int r = (int)__builtin_ctzll(cand);
          uint64_t sr = readlane64(dw, r);
          uint64_t m = sr & ~((2ull << r) - 1ull);   // cols strictly > r
          cand &= ~(1ull << r);
          cand &= ~m;
          bk   &= ~m;
        }
      }
      if (lane == 0) keep_s[k] = bk;
      if (k + 1 < W) dw = diag64[(size_t)(k + 1) * 64 + lane];  // prefetch next diag

      // ---- apply block k: lane handles word wd = k+1+lane ----
      const int wd = k + 1 + lane;
      uint64_t acc = 0;
      {
        uint64_t remc = bkw;
        #pragma unroll
        for (int s = 0; s < CSLOT; ++s) {
          int r = remc ? (int)__builtin_ctzll(remc) : 0;
          uint64_t mk = (uint64_t)0 - (uint64_t)((remc != 0) && ((bk >> r) & 1ull));
          remc &= remc - 1;
          acc |= pre[s] & mk;
        }
      }
      // overflow: only KEPT candidates beyond CSLOT (rare, first blocks only)
      {
        uint64_t remo = ovw & bk;
        const size_t rowbase = (size_t)k * 64;
        while (remo) {
          int r0 = (int)__builtin_ctzll(remo); remo &= remo - 1;
          uint64_t m1 = (uint64_t)0 - (uint64_t)(remo != 0);
          int r1 = remo ? (int)__builtin_ctzll(remo) : r0; remo &= remo - 1;
          uint64_t m2 = (uint64_t)0 - (uint64_t)(remo != 0);
          int r2 = remo ? (int)__builtin_ctzll(remo) : r0; remo &= remo - 1;
          uint64_t m3 = (uint64_t)0 - (uint64_t)(remo != 0);
          int r3 = remo ? (int)__builtin_ctzll(remo) : r0; remo &= remo - 1;
          uint64_t m4 = (uint64_t)0 - (uint64_t)(remo != 0);
          int r4 = remo ? (int)__builtin_ctzll(remo) : r0; remo &= remo - 1;
          uint64_t m5 = (uint64_t)0 - (uint64_t)(remo != 0);
          int r5 = remo ? (int)__builtin_ctzll(remo) : r0; remo &= remo - 1;
          uint64_t m6 = (uint64_t)0 - (uint64_t)(remo != 0);
          int r6 = remo ? (int)__builtin_ctzll(remo) : r0; remo &= remo - 1;
          uint64_t m7 = (uint64_t)0 - (uint64_t)(remo != 0);
          int r7 = remo ? (int)__builtin_ctzll(remo) : r0; remo &= remo - 1;
          if (wd < W) {
            uint64_t v0 = sup[(rowbase + r0) * Wp + wd];
            uint64_t v1 = sup[(rowbase + r1) * Wp + wd];
            uint64_t v2 = sup[(rowbase + r2) * Wp + wd];
            uint64_t v3 = sup[(rowbase + r3) * Wp + wd];
            uint64_t v4 = sup[(rowbase + r4) * Wp + wd];
            uint64_t v5 = sup[(rowbase + r5) * Wp + wd];
            uint64_t v6 = sup[(rowbase + r6) * Wp + wd];
            uint64_t v7 = sup[(rowbase + r7) * Wp + wd];
            acc |= v0 | (v1 & m1) | (v2 & m2) | (v3 & m3)
                      | (v4 & m4) | (v5 & m5) | (v6 & m6) | (v7 & m7);
          }
        }
      }
      if (wd < W) keep_s[wd] &= ~acc;

      // ---- tail words beyond 64-lane coverage (k=0 only for W=66) ----
      for (int wd2 = k + 65; wd2 < W; ++wd2) {
        uint64_t v = 0;
        if ((bk >> lane) & 1ull) v = sup[((size_t)k * 64 + lane) * Wp + wd2];
        v |= shflxor64(v, 1);  v |= shflxor64(v, 2);  v |= shflxor64(v, 4);
        v |= shflxor64(v, 8);  v |= shflxor64(v, 16); v |= shflxor64(v, 32);
        if (lane == 0) keep_s[wd2] &= ~v;
      }

      // ---- read next candidate word (post-apply => exact pre-resolve word) and
      //      issue register prefetch for block k+1 ----
      if (k + 1 < W) {
        bkw = firstlane64(keep_s[k + 1]);
        uint64_t remc = bkw;
        const int wdn = k + 2 + lane;
        const size_t rb = (size_t)(k + 1) * 64;
        #pragma unroll
        for (int s = 0; s < CSLOT; ++s) {
          int r = remc ? (int)__builtin_ctzll(remc) : 0;
          bool valid = (remc != 0);
          remc &= remc - 1;
          pre[s] = (valid && wdn < W) ? sup[(rb + r) * Wp + wdn] : 0ull;
        }
        ovw = remc;
      }
    }
  }
  __syncthreads();

  // ---- emit output (all 8 waves) ----
  for (int r = tid; r < N_ANCH; r += NT) {
    bool kept = (r < nv) && ((keep_s[r >> 6] >> (r & 63)) & 1ull);
    float4 b = kept ? boxes_s[r] : make_float4(0.f, 0.f, 0.f, 0.f);
    float s = kept ? scores_s[r] : 0.0f;
    out[r * 5 + 0] = b.x;
    out[r * 5 + 1] = b.y;
    out[r * 5 + 2] = b.z;
    out[r * 5 + 3] = b.w;
    out[r * 5 + 4] = s;
  }
}

extern "C" void kernel_launch(void* const* d_in, const int* in_sizes, int n_in,
                              void* d_out, int out_size, void* d_ws, size_t ws_size,
                              hipStream_t stream) {
  const float* in = (const float*)d_in[0];
  float* out = (float*)d_out;
  uint8_t* ws = (uint8_t*)d_ws;
  unsigned* nvp = (unsigned*)ws;                                       // 64 B
  float* scores_s = (float*)(ws + 64);                                 // 33600 B
  float4* boxes_s = (float4*)(ws + 64 + 33600);                        // NB*16 = 135168 B
  unsigned long long* diag = (unsigned long long*)(ws + 64 + 33600 + (size_t)NB * 16);   // NB*8
  unsigned long long* sup  = (unsigned long long*)(ws + 64 + 33600 + (size_t)NB * 24);   // ~2.3 MB

  (void)hipMemsetAsync(ws, 0, 64, stream);
  k_rank<<<dim3(WMAX), dim3(256), 0, stream>>>(in, scores_s, boxes_s, nvp);
  k_sup<<<dim3(WMAX, (N_ANCH + 255) / 256), dim3(256), 0, stream>>>(boxes_s, nvp, sup, diag);
  k_scan<<<dim3(1), dim3(NT), 0, stream>>>(scores_s, boxes_s, sup, diag, nvp, out);
}